// Round 1
// baseline (120.109 us; speedup 1.0000x reference)
//
#include <hip/hip_runtime.h>
#include <math.h>

#define A_W 200.0f
#define B_BATCH 16
#define N_PTS 65536
#define C_CLS 5
#define BN (B_BATCH * N_PTS)

#define BPB 64                       // stat blocks per batch
#define STAT_BLOCKS (B_BATCH * BPB)  // 1024
#define NLL_BLOCKS 512
#define TPB 256

// ws layout (floats):
//  [0 .. 255]   per-batch stats: for b: gt_cnt[4], pr_cnt[4], gt_z[4], pr_z[4]
//  [256 .. 260] s[5]   (segment sum of nll)
//  [261 .. 265] n[5]   (segment counts)
//  ((int*)ws)[272]     flag: 1 = target_previous is int32 layout, 0 = int64

__device__ inline float wave_reduce_f(float v) {
#pragma unroll
    for (int off = 32; off > 0; off >>= 1)
        v += __shfl_down(v, off, 64);
    return v;
}

__global__ void init_kernel(float* __restrict__ ws,
                            const unsigned* __restrict__ tprev_u32) {
    int t = threadIdx.x;
    if (t < 272) ws[t] = 0.0f;
    if (t == 0) {
        // int32 layout => odd words are values in [0,5), ~certainly one nonzero.
        // int64 layout => odd words are high words, all zero.
        int is32 = 0;
        for (int i = 0; i < 64; ++i)
            is32 |= (tprev_u32[2 * i + 1] != 0u) ? 1 : 0;
        ((int*)ws)[272] = is32;
    }
}

__global__ __launch_bounds__(TPB)
void main_kernel(const float* __restrict__ pred,
                 const int* __restrict__ target,
                 const float* __restrict__ points,
                 const float* __restrict__ prev,
                 const void* __restrict__ tprev,
                 float* __restrict__ ws) {
    __shared__ float sm[16];
    const int bid = blockIdx.x;
    const int tid = threadIdx.x;
    const int lane = tid & 63;

    if (bid < STAT_BLOCKS) {
        // ---- per-batch stats: argmax(pred), counts and z-sums per class ----
        const int b = bid / BPB;
        const int chunk = bid % BPB;
        const int per = N_PTS / BPB;       // 1024
        const int n0 = chunk * per;
        const float* __restrict__ predb = pred + (size_t)b * N_PTS * C_CLS;
        const int* __restrict__ tgtb = target + (size_t)b * N_PTS;
        const float* __restrict__ ptsb = points + (size_t)b * N_PTS * 9;

        float gc0 = 0, gc1 = 0, gc2 = 0, gc3 = 0;
        float pc0 = 0, pc1 = 0, pc2 = 0, pc3 = 0;
        float gz0 = 0, gz1 = 0, gz2 = 0, gz3 = 0;
        float pz0 = 0, pz1 = 0, pz2 = 0, pz3 = 0;

        for (int n = n0 + tid; n < n0 + per; n += TPB) {
            const float* p = predb + (size_t)n * C_CLS;
            float x0 = p[0], x1 = p[1], x2 = p[2], x3 = p[3], x4 = p[4];
            int am = 0;
            float bv = x0;
            if (x1 > bv) { bv = x1; am = 1; }
            if (x2 > bv) { bv = x2; am = 2; }
            if (x3 > bv) { bv = x3; am = 3; }
            if (x4 > bv) { bv = x4; am = 4; }
            float z = ptsb[(size_t)n * 9 + 2];
            int t = tgtb[n];
            if (t == 0) { gc0 += 1.f; gz0 += z; }
            else if (t == 1) { gc1 += 1.f; gz1 += z; }
            else if (t == 2) { gc2 += 1.f; gz2 += z; }
            else if (t == 3) { gc3 += 1.f; gz3 += z; }
            if (am == 0) { pc0 += 1.f; pz0 += z; }
            else if (am == 1) { pc1 += 1.f; pz1 += z; }
            else if (am == 2) { pc2 += 1.f; pz2 += z; }
            else if (am == 3) { pc3 += 1.f; pz3 += z; }
        }

        if (tid < 16) sm[tid] = 0.0f;
        __syncthreads();

        float vals[16] = {gc0, gc1, gc2, gc3, pc0, pc1, pc2, pc3,
                          gz0, gz1, gz2, gz3, pz0, pz1, pz2, pz3};
#pragma unroll
        for (int k = 0; k < 16; ++k) {
            float r = wave_reduce_f(vals[k]);
            if (lane == 0) atomicAdd(&sm[k], r);
        }
        __syncthreads();
        if (tid < 16) atomicAdd(&ws[b * 16 + tid], sm[tid]);
    } else {
        // ---- NLL + segment sums over pred_previous / target_previous ----
        const int nb = bid - STAT_BLOCKS;
        const int per = BN / NLL_BLOCKS;   // 2048
        const int k0 = nb * per;
        const int flag32 = ((const int*)ws)[272];
        const int* __restrict__ tp32 = (const int*)tprev;
        const long long* __restrict__ tp64 = (const long long*)tprev;

        float s0 = 0, s1 = 0, s2 = 0, s3 = 0, s4 = 0;
        float c0 = 0, c1 = 0, c2 = 0, c3 = 0, c4 = 0;

        for (int k = k0 + tid; k < k0 + per; k += TPB) {
            const float* x = prev + (size_t)k * C_CLS;
            float x0 = x[0], x1 = x[1], x2 = x[2], x3 = x[3], x4 = x[4];
            float m = fmaxf(fmaxf(fmaxf(x0, x1), fmaxf(x2, x3)), x4);
            float e = expf(x0 - m) + expf(x1 - m) + expf(x2 - m) +
                      expf(x3 - m) + expf(x4 - m);
            float lse = m + logf(e);
            int t = flag32 ? tp32[k] : (int)tp64[k];
            float xt = x0;
            xt = (t == 1) ? x1 : xt;
            xt = (t == 2) ? x2 : xt;
            xt = (t == 3) ? x3 : xt;
            xt = (t == 4) ? x4 : xt;
            float nll = lse - xt;
            if (t == 0) { s0 += nll; c0 += 1.f; }
            else if (t == 1) { s1 += nll; c1 += 1.f; }
            else if (t == 2) { s2 += nll; c2 += 1.f; }
            else if (t == 3) { s3 += nll; c3 += 1.f; }
            else { s4 += nll; c4 += 1.f; }
        }

        if (tid < 16) sm[tid] = 0.0f;
        __syncthreads();

        float vals[10] = {s0, s1, s2, s3, s4, c0, c1, c2, c3, c4};
#pragma unroll
        for (int k = 0; k < 10; ++k) {
            float r = wave_reduce_f(vals[k]);
            if (lane == 0) atomicAdd(&sm[k], r);
        }
        __syncthreads();
        if (tid < 10) atomicAdd(&ws[256 + tid], sm[tid]);
    }
}

__global__ void final_kernel(const float* __restrict__ ws,
                             float* __restrict__ out) {
    const int lane = threadIdx.x;
    float loss = 0.0f;
    if (lane < B_BATCH) {
        const float* st = ws + lane * 16;
        float gc[4], pc[4], gz[4], pz[4];
        bool GT[4], PR[4];
        float gm[4], pm[4];
        float w[5] = {1.f, 1.f, 1.f, 1.f, 1.f};
#pragma unroll
        for (int c = 0; c < 4; ++c) {
            gc[c] = st[c];
            pc[c] = st[4 + c];
            gz[c] = st[8 + c];
            pz[c] = st[12 + c];
            GT[c] = gc[c] > 0.0f;
            PR[c] = pc[c] > 0.0f;
            gm[c] = gz[c] / fmaxf(gc[c], 1.0f);
            pm[c] = pz[c] / fmaxf(pc[c], 1.0f);
            if (!GT[c] && PR[c]) w[c] += A_W;
        }
#define PAIR(i, j, mlt)                                                        \
        {                                                                      \
            bool cond = GT[i] && PR[i] && GT[j] && PR[j] &&                    \
                        (gm[i] < gm[j]) && (pm[i] >= pm[j]);                   \
            float add = (mlt) * A_W * (cond ? 1.0f : 0.0f);                    \
            w[i] += add;                                                       \
            w[j] += add;                                                       \
        }
        PAIR(0, 1, 1.0f)
        PAIR(1, 2, 1.0f)
        PAIR(2, 3, 1.0f)
        PAIR(0, 2, 2.0f)
        PAIR(1, 3, 2.0f)
        PAIR(0, 3, 3.0f)
#undef PAIR
        const float* s = ws + 256;
        const float* n = ws + 261;
        float num = 0.0f, den = 0.0f;
#pragma unroll
        for (int c = 0; c < C_CLS; ++c) {
            num += w[c] * s[c];
            den += w[c] * n[c];
        }
        loss = num / den;
    }
#pragma unroll
    for (int off = 8; off > 0; off >>= 1)
        loss += __shfl_down(loss, off, 64);
    if (lane == 0) out[0] = loss;
}

extern "C" void kernel_launch(void* const* d_in, const int* in_sizes, int n_in,
                              void* d_out, int out_size, void* d_ws, size_t ws_size,
                              hipStream_t stream) {
    const float* pred = (const float*)d_in[0];
    const int* target = (const int*)d_in[1];
    const float* points = (const float*)d_in[2];
    const float* prev = (const float*)d_in[3];
    const void* tprev = d_in[4];
    float* ws = (float*)d_ws;
    float* out = (float*)d_out;

    hipLaunchKernelGGL(init_kernel, dim3(1), dim3(TPB), 0, stream,
                       ws, (const unsigned*)tprev);
    hipLaunchKernelGGL(main_kernel, dim3(STAT_BLOCKS + NLL_BLOCKS), dim3(TPB),
                       0, stream, pred, target, points, prev, tprev, ws);
    hipLaunchKernelGGL(final_kernel, dim3(1), dim3(64), 0, stream, ws, out);
}

// Round 2
// 116.411 us; speedup vs baseline: 1.0318x; 1.0318x over previous
//
#include <hip/hip_runtime.h>
#include <math.h>

#define A_W 200.0f
#define B_BATCH 16
#define N_PTS 65536
#define C_CLS 5
#define BN (B_BATCH * N_PTS)

#define STAT_BLOCKS 1024   // 64 blocks per batch, 1024 points each, 4 pts/thread
#define NLL_BLOCKS 1024    // 1024 elements each, 4 elems/thread
#define TPB 256
#define NLL_BASE 16384     // float offset in ws for NLL partials

// ws layout (floats):
//  [0 .. 16383]              stat partials: block bid writes 16 floats at bid*16
//                            order: gc0..3, pc0..3, gz0..3, pz0..3
//  [16384 .. 16384+10239]    NLL partials, transposed: value v at NLL_BASE + v*1024 + nb
//                            v: 0..4 = nll sums s0..s4, 5..9 = counts c0..c4

__device__ inline float wave_reduce_f(float v) {
#pragma unroll
    for (int off = 32; off > 0; off >>= 1)
        v += __shfl_down(v, off, 64);
    return v;
}

__global__ __launch_bounds__(TPB)
void main_kernel(const float* __restrict__ pred,
                 const int* __restrict__ target,
                 const float* __restrict__ points,
                 const float* __restrict__ prev,
                 const unsigned* __restrict__ tprev_u32,
                 float* __restrict__ ws) {
    __shared__ float sm[16];
    __shared__ int sflag;
    const int bid = blockIdx.x;
    const int tid = threadIdx.x;
    const int lane = tid & 63;
    const int wv = tid >> 6;

    if (tid < 16) sm[tid] = 0.0f;

    // NLL blocks: detect int32 vs int64 layout of target_previous by probing
    // the first 64 odd dwords (high words if int64 layout -> all zero;
    // int32 layout -> values in [0,5), P(all zero) ~ 0.2^64 ~ 0).
    // First 512 B is in-bounds for both layouts; all blocks hit same L2 lines.
    if (bid >= STAT_BLOCKS && wv == 0) {
        unsigned w = tprev_u32[2 * lane + 1];
        unsigned long long bal = __ballot(w != 0u);
        if (tid == 0) sflag = (bal != 0ull) ? 1 : 0;
    }
    __syncthreads();

    if (bid < STAT_BLOCKS) {
        // ---- per-batch stats over pred/target/points ----
        const int b = bid >> 6;
        const int chunk = bid & 63;
        const size_t n0 = (size_t)b * N_PTS + (size_t)chunk * 1024 + (size_t)tid * 4;

        const float4* __restrict__ p4 = (const float4*)(pred + n0 * 5);
        float4 q0 = p4[0], q1 = p4[1], q2 = p4[2], q3 = p4[3], q4 = p4[4];
        const int4 tg = *(const int4*)(target + n0);
        const float* __restrict__ pb = points + n0 * 9;
        float zv[4] = {pb[2], pb[11], pb[20], pb[29]};

        float xs[4][5] = {
            {q0.x, q0.y, q0.z, q0.w, q1.x},
            {q1.y, q1.z, q1.w, q2.x, q2.y},
            {q2.z, q2.w, q3.x, q3.y, q3.z},
            {q3.w, q4.x, q4.y, q4.z, q4.w}};
        int tgt[4] = {tg.x, tg.y, tg.z, tg.w};

        float gc0 = 0, gc1 = 0, gc2 = 0, gc3 = 0;
        float pc0 = 0, pc1 = 0, pc2 = 0, pc3 = 0;
        float gz0 = 0, gz1 = 0, gz2 = 0, gz3 = 0;
        float pz0 = 0, pz1 = 0, pz2 = 0, pz3 = 0;

#pragma unroll
        for (int j = 0; j < 4; ++j) {
            float x0 = xs[j][0], x1 = xs[j][1], x2 = xs[j][2],
                  x3 = xs[j][3], x4 = xs[j][4];
            int am = 0;
            float bv = x0;
            if (x1 > bv) { bv = x1; am = 1; }
            if (x2 > bv) { bv = x2; am = 2; }
            if (x3 > bv) { bv = x3; am = 3; }
            if (x4 > bv) { bv = x4; am = 4; }
            float z = zv[j];
            int t = tgt[j];
            if (t == 0) { gc0 += 1.f; gz0 += z; }
            else if (t == 1) { gc1 += 1.f; gz1 += z; }
            else if (t == 2) { gc2 += 1.f; gz2 += z; }
            else if (t == 3) { gc3 += 1.f; gz3 += z; }
            if (am == 0) { pc0 += 1.f; pz0 += z; }
            else if (am == 1) { pc1 += 1.f; pz1 += z; }
            else if (am == 2) { pc2 += 1.f; pz2 += z; }
            else if (am == 3) { pc3 += 1.f; pz3 += z; }
        }

        float vals[16] = {gc0, gc1, gc2, gc3, pc0, pc1, pc2, pc3,
                          gz0, gz1, gz2, gz3, pz0, pz1, pz2, pz3};
#pragma unroll
        for (int k = 0; k < 16; ++k) {
            float r = wave_reduce_f(vals[k]);
            if (lane == 0) atomicAdd(&sm[k], r);
        }
        __syncthreads();
        if (tid < 16) ws[(size_t)bid * 16 + tid] = sm[tid];
    } else {
        // ---- NLL + segment sums over pred_previous / target_previous ----
        const int nb = bid - STAT_BLOCKS;
        const size_t k0 = (size_t)nb * 1024 + (size_t)tid * 4;
        const int is32 = sflag;

        const float4* __restrict__ p4 = (const float4*)(prev + k0 * 5);
        float4 q0 = p4[0], q1 = p4[1], q2 = p4[2], q3 = p4[3], q4 = p4[4];

        int tgt[4];
        if (is32) {
            int4 tt = *(const int4*)((const int*)tprev_u32 + k0);
            tgt[0] = tt.x; tgt[1] = tt.y; tgt[2] = tt.z; tgt[3] = tt.w;
        } else {
            int4 a = *(const int4*)((const int*)tprev_u32 + 2 * k0);
            int4 c = *(const int4*)((const int*)tprev_u32 + 2 * k0 + 4);
            tgt[0] = a.x; tgt[1] = a.z; tgt[2] = c.x; tgt[3] = c.z;
        }

        float xs[4][5] = {
            {q0.x, q0.y, q0.z, q0.w, q1.x},
            {q1.y, q1.z, q1.w, q2.x, q2.y},
            {q2.z, q2.w, q3.x, q3.y, q3.z},
            {q3.w, q4.x, q4.y, q4.z, q4.w}};

        float s0 = 0, s1 = 0, s2 = 0, s3 = 0, s4 = 0;
        float c0 = 0, c1 = 0, c2 = 0, c3 = 0, c4 = 0;

#pragma unroll
        for (int j = 0; j < 4; ++j) {
            float x0 = xs[j][0], x1 = xs[j][1], x2 = xs[j][2],
                  x3 = xs[j][3], x4 = xs[j][4];
            float m = fmaxf(fmaxf(fmaxf(x0, x1), fmaxf(x2, x3)), x4);
            float e = expf(x0 - m) + expf(x1 - m) + expf(x2 - m) +
                      expf(x3 - m) + expf(x4 - m);
            float lse = m + logf(e);
            int t = tgt[j];
            float xt = x0;
            xt = (t == 1) ? x1 : xt;
            xt = (t == 2) ? x2 : xt;
            xt = (t == 3) ? x3 : xt;
            xt = (t == 4) ? x4 : xt;
            float nll = lse - xt;
            if (t == 0) { s0 += nll; c0 += 1.f; }
            else if (t == 1) { s1 += nll; c1 += 1.f; }
            else if (t == 2) { s2 += nll; c2 += 1.f; }
            else if (t == 3) { s3 += nll; c3 += 1.f; }
            else { s4 += nll; c4 += 1.f; }
        }

        float vals[10] = {s0, s1, s2, s3, s4, c0, c1, c2, c3, c4};
#pragma unroll
        for (int k = 0; k < 10; ++k) {
            float r = wave_reduce_f(vals[k]);
            if (lane == 0) atomicAdd(&sm[k], r);
        }
        __syncthreads();
        if (tid < 10) ws[NLL_BASE + (size_t)tid * 1024 + nb] = sm[tid];
    }
}

__global__ __launch_bounds__(1024)
void final_kernel(const float* __restrict__ ws, float* __restrict__ out) {
    __shared__ float stat[256];
    __shared__ float sn[10];
    const int t = threadIdx.x;
    const int lane = t & 63;
    const int wv = t >> 6;

    if (t < 256) {
        // stat[b*16 + v] = sum over 64 chunk-partials of batch b, value v
        const int b = t >> 4, v = t & 15;
        const float* p = ws + (size_t)(b * 64) * 16 + v;
        float s = 0.0f;
#pragma unroll 8
        for (int i = 0; i < 64; ++i) s += p[(size_t)i * 16];
        stat[t] = s;
    }
    if (wv >= 4 && wv < 14) {
        // sn[v] = sum over 1024 NLL partials of value v
        const int v = wv - 4;
        const float* p = ws + NLL_BASE + (size_t)v * 1024;
        float s = 0.0f;
#pragma unroll
        for (int k = 0; k < 16; ++k) s += p[lane + 64 * k];
        s = wave_reduce_f(s);
        if (lane == 0) sn[v] = s;
    }
    __syncthreads();

    float loss = 0.0f;
    if (t < B_BATCH) {
        const float* st = stat + t * 16;
        float gc[4], pc[4], gm[4], pm[4];
        bool GT[4], PR[4];
        float w[5] = {1.f, 1.f, 1.f, 1.f, 1.f};
#pragma unroll
        for (int c = 0; c < 4; ++c) {
            gc[c] = st[c];
            pc[c] = st[4 + c];
            GT[c] = gc[c] > 0.0f;
            PR[c] = pc[c] > 0.0f;
            gm[c] = st[8 + c] / fmaxf(gc[c], 1.0f);
            pm[c] = st[12 + c] / fmaxf(pc[c], 1.0f);
            if (!GT[c] && PR[c]) w[c] += A_W;
        }
#define PAIR(i, j, mlt)                                                        \
        {                                                                      \
            bool cond = GT[i] && PR[i] && GT[j] && PR[j] &&                    \
                        (gm[i] < gm[j]) && (pm[i] >= pm[j]);                   \
            float add = (mlt) * A_W * (cond ? 1.0f : 0.0f);                    \
            w[i] += add;                                                       \
            w[j] += add;                                                       \
        }
        PAIR(0, 1, 1.0f)
        PAIR(1, 2, 1.0f)
        PAIR(2, 3, 1.0f)
        PAIR(0, 2, 2.0f)
        PAIR(1, 3, 2.0f)
        PAIR(0, 3, 3.0f)
#undef PAIR
        float num = 0.0f, den = 0.0f;
#pragma unroll
        for (int c = 0; c < C_CLS; ++c) {
            num += w[c] * sn[c];
            den += w[c] * sn[5 + c];
        }
        loss = num / den;
    }
    if (wv == 0) {
#pragma unroll
        for (int off = 8; off > 0; off >>= 1)
            loss += __shfl_down(loss, off, 64);
        if (t == 0) out[0] = loss;
    }
}

extern "C" void kernel_launch(void* const* d_in, const int* in_sizes, int n_in,
                              void* d_out, int out_size, void* d_ws, size_t ws_size,
                              hipStream_t stream) {
    const float* pred = (const float*)d_in[0];
    const int* target = (const int*)d_in[1];
    const float* points = (const float*)d_in[2];
    const float* prev = (const float*)d_in[3];
    const unsigned* tprev = (const unsigned*)d_in[4];
    float* ws = (float*)d_ws;
    float* out = (float*)d_out;

    hipLaunchKernelGGL(main_kernel, dim3(STAT_BLOCKS + NLL_BLOCKS), dim3(TPB),
                       0, stream, pred, target, points, prev, tprev, ws);
    hipLaunchKernelGGL(final_kernel, dim3(1), dim3(1024), 0, stream, ws, out);
}